// Round 2
// baseline (70925.446 us; speedup 1.0000x reference)
//
#include <hip/hip_runtime.h>

#define KUc 512
#define Hc 90
#define H3c 270
#define Bc 32
#define Tc 64
#define ROWSc 64
#define NBLK 256
#define BLKT 512
#define MMT 184      // matmul threads: rowg=tid/23 (0..7), colg=tid%23
#define HBASE 192    // helper threads 192..511 (waves 3..7)
#define NHW 5
#define BSLOT 23     // active-row slots per batch
#define NBCAP 64

__device__ __forceinline__ float sigf(float x) { return 1.0f / (1.0f + __expf(-x)); }
__device__ __forceinline__ float tanhf_(float x) {
    float e = __expf(2.0f * x);
    return 1.0f - 2.0f / (e + 1.0f);
}
// swizzled LDS address for state element (h-dim index h, row r): breaks the
// stride-256B bank collision between matmul reads and GRU writes.
__device__ __forceinline__ int hadr(int h, int r) {
    return (h << 6) + ((((r >> 3) ^ ((h >> 2) & 7))) << 3) + (r & 7);
}

__device__ __forceinline__ void gridbar(unsigned* bar, int ep) {
    __threadfence();              // release this thread's global writes
    __syncthreads();
    if (threadIdx.x == 0) {
        unsigned r = atomicAdd(&bar[0], 1u);
        if (r == (unsigned)(NBLK * ep) - 1u) {
            atomicExch(&bar[16], (unsigned)ep);
        } else {
            while (atomicAdd(&bar[16], 0u) < (unsigned)ep) __builtin_amdgcn_s_sleep(8);
        }
    }
    __syncthreads();
    __threadfence();              // acquire: see other blocks' writes
}

#define MM_CHUNK(K0, K1)                                                        \
    {                                                                           \
        _Pragma("unroll 2") for (int kk = (K0); kk < (K1); ++kk) {              \
            const int hb = (kk << 6) + ((rowg ^ ((kk >> 2) & 7)) << 3);         \
            const float4 ha = *(const float4*)&h_sT[hb];                        \
            const float4 hbv = *(const float4*)&h_sT[hb + 4];                   \
            const int wb = kk * 92 + (colg << 2);                               \
            const float4 wr = *(const float4*)&whR[wb];                         \
            const float4 wz = *(const float4*)&whZ[wb];                         \
            const float4 wg = *(const float4*)&whG[wb];                         \
            const float hv[8] = {ha.x, ha.y, ha.z, ha.w,                        \
                                 hbv.x, hbv.y, hbv.z, hbv.w};                   \
            _Pragma("unroll") for (int rr = 0; rr < 8; ++rr) {                  \
                accR[rr][0] += hv[rr] * wr.x; accR[rr][1] += hv[rr] * wr.y;     \
                accR[rr][2] += hv[rr] * wr.z; accR[rr][3] += hv[rr] * wr.w;     \
                accZ[rr][0] += hv[rr] * wz.x; accZ[rr][1] += hv[rr] * wz.y;     \
                accZ[rr][2] += hv[rr] * wz.z; accZ[rr][3] += hv[rr] * wz.w;     \
                accG[rr][0] += hv[rr] * wg.x; accG[rr][1] += hv[rr] * wg.y;     \
                accG[rr][2] += hv[rr] * wg.z; accG[rr][3] += hv[rr] * wg.w;     \
            }                                                                   \
        }                                                                       \
    }

__global__ __launch_bounds__(BLKT, 2) void skt_persist(
    const int* __restrict__ qs, const int* __restrict__ as_,
    const float* __restrict__ response_emb, const float* __restrict__ concept_emb,
    const float* __restrict__ nb_adj, const float* __restrict__ succ_adj,
    const float* __restrict__ Wi_self, const float* __restrict__ Wh_self,
    const float* __restrict__ bi_self, const float* __restrict__ bh_self,
    const float* __restrict__ Wi_rnn, const float* __restrict__ Wh_rnn,
    const float* __restrict__ bi_rnn, const float* __restrict__ bh_rnn,
    const float* __restrict__ W_sync, const float* __restrict__ b_sync,
    const float* __restrict__ W_prop, const float* __restrict__ b_prop,
    const float* __restrict__ W_agg, const float* __restrict__ b_agg,
    const float* __restrict__ W_out, const float* __restrict__ b_out,
    float* __restrict__ out, float* __restrict__ stA, float* __restrict__ stB,
    float* __restrict__ ce_ws, unsigned* __restrict__ bar) {

    __shared__ alignas(16) float whR[90 * 92], whZ[90 * 92], whG[90 * 92];
    __shared__ alignas(16) float h_sT[90 * 64];
    __shared__ float gibuf[(1 + BSLOT) * 273];
    __shared__ float gia[H3c], gha[H3c];
    __shared__ float ss_s[Hc], ceq_s[Hc], ns_s[Hc], nsync_s[Hc], pvec_s[Hc], reflec_s[Hc];
    __shared__ float reflp[NHW][92];
    __shared__ float actw[NHW][92], infw[NHW][92];
    __shared__ float nbv_s[ROWSc], sv_s[ROWSc];
    __shared__ int rowslot[ROWSc], list_s[ROWSc];
    __shared__ int nblist[NBCAP];
    __shared__ float wout_s[Hc];
    __shared__ int cnt_s[2];   // [0]=nact, [1]=nnb
    __shared__ float bout_s;

    const int tid = threadIdx.x;
    const int bb = blockIdx.x >> 3;
    const int k0 = (blockIdx.x & 7) * ROWSc;
    const bool mm = (tid < MMT);
    const int rowg = mm ? (tid / 23) : 0;
    const int colg = mm ? (tid - rowg * 23) : 0;
    const bool hp = (tid >= HBASE);
    const int hidx = hp ? (tid - HBASE) : 0;
    const int hw = hidx >> 6;
    const int hl = hidx & 63;

    // ================= PREP (once) =================
    for (int i = tid; i < 90 * 64; i += BLKT) h_sT[i] = 0.0f;
    for (int i = tid; i < 90 * 92; i += BLKT) {
        int kk = i / 92, c = i - kk * 92;
        whR[i] = (c < 90) ? Wh_rnn[kk * H3c + c] : 0.0f;
        whZ[i] = (c < 90) ? Wh_rnn[kk * H3c + 90 + c] : 0.0f;
        whG[i] = (c < 90) ? Wh_rnn[kk * H3c + 180 + c] : 0.0f;
    }
    if (tid < Hc) { ns_s[tid] = fmaxf(b_agg[tid], 0.0f); wout_s[tid] = W_out[tid]; }
    if (tid == 0) { bout_s = b_out[0]; cnt_s[0] = 0; cnt_s[1] = 0; }
    __syncthreads();
    for (int c = tid; c < H3c; c += BLKT) {     // gibuf slot 0 = gi0 (+ bh folded)
        float acc = bi_rnn[c] + bh_rnn[c];
        for (int kk = 0; kk < Hc; ++kk) acc += ns_s[kk] * Wi_rnn[kk * H3c + c];
        gibuf[c] = acc;
    }
    if (tid < 180) {                            // ce_sync rows 2*bid, 2*bid+1
        int r = tid / 90, m = tid - r * 90;
        int k = blockIdx.x * 2 + r;
        float acc = b_sync[m];
        for (int kk = 0; kk < Hc; ++kk)
            acc += concept_emb[k * Hc + kk] * W_sync[(180 + kk) * Hc + m];
        ce_ws[k * Hc + m] = acc;
    }
    gridbar(bar, 1);

    // ================= TIME LOOP =================
    for (int t = 0; t < Tc; ++t) {
        const float* stIn = (t & 1) ? stB : stA;
        float* stOut = (t & 1) ? stA : stB;
        const int q = qs[bb * Tc + t];
        const int a = as_[bb * Tc + t];
        const bool owner = (q >= k0 && q < k0 + ROWSc);

        float accR[8][4], accZ[8][4], accG[8][4];
        if (mm) {
#pragma unroll
            for (int rr = 0; rr < 8; ++rr)
#pragma unroll
                for (int j = 0; j < 4; ++j) { accR[rr][j] = 0.f; accZ[rr][j] = 0.f; accG[rr][j] = 0.f; }
        }

        auto chainRows = [&](int batch, int mode) {   // mode 0: skip q, 1: only q, 2: all
            int nact = cnt_s[0];
            int e0 = batch * BSLOT;
            int e1 = e0 + BSLOT; if (e1 > nact) e1 = nact;
            for (int e = e0 + hw; e < e1; e += NHW) {
                int r = list_s[e];
                bool isq = (k0 + r == q);
                if (mode == 0 && isq) continue;
                if (mode == 1 && !isq) continue;
                const int k = k0 + r;
                const float nv = nbv_s[r], sv = sv_s[r];
                const int slot = 1 + (e - e0);
#pragma unroll
                for (int mb = 0; mb < 2; ++mb) {
                    int m = mb * 64 + hl;
                    if (m < Hc) {
                        float s = 0.0f;
                        if (nv != 0.0f) {
                            float acc = nsync_s[m] + ce_ws[(size_t)k * Hc + m];
                            for (int kk = 0; kk < Hc; ++kk)
                                acc += h_sT[hadr(kk, r)] * W_sync[kk * Hc + m];
                            s = nv * fmaxf(acc, 0.0f);
                        }
                        if (isq) s += reflec_s[m];
                        actw[hw][m] = 0.5f * s + 0.5f * sv * pvec_s[m];
                    }
                }
#pragma unroll
                for (int mb = 0; mb < 2; ++mb) {
                    int m = mb * 64 + hl;
                    if (m < Hc) {
                        float acc = b_agg[m];
                        for (int kk = 0; kk < Hc; ++kk) acc += actw[hw][kk] * W_agg[kk * Hc + m];
                        infw[hw][m] = fmaxf(acc, 0.0f);
                    }
                }
#pragma unroll
                for (int cb = 0; cb < 5; ++cb) {
                    int c = cb * 64 + hl;
                    if (c < H3c) {
                        float acc = bi_rnn[c] + bh_rnn[c];
                        for (int kk = 0; kk < Hc; ++kk) acc += infw[hw][kk] * Wi_rnn[kk * H3c + c];
                        gibuf[slot * 273 + c] = acc;
                    }
                }
            }
        };

        auto applyPass = [&](int pass, float* stO) {
#pragma unroll
            for (int rr = 0; rr < 8; ++rr) {
                const int row = rowg * 8 + rr;
                const int sraw = rowslot[row];
                const int pb = (sraw == 0) ? 0 : (sraw - 1) / BSLOT;
                if (pb != pass) continue;
                const int gib = ((sraw == 0) ? 0 : (1 + (sraw - 1) % BSLOT)) * 273;
                float hnv[4] = {0.f, 0.f, 0.f, 0.f};
#pragma unroll
                for (int j = 0; j < 4; ++j) {
                    int m = (colg << 2) + j;
                    if (m < Hc) {
                        int ad = hadr(m, row);
                        float hold = h_sT[ad];
                        float rg = sigf(gibuf[gib + m] + accR[rr][j]);
                        float zg = sigf(gibuf[gib + 90 + m] + accZ[rr][j]);
                        float gg = tanhf_(gibuf[gib + 180 + m] + rg * accG[rr][j]);
                        float v = (1.0f - zg) * gg + zg * hold;
                        h_sT[ad] = v;
                        hnv[j] = v;
                    }
                }
                size_t gb = ((size_t)(bb * KUc + k0 + row)) * Hc + (colg << 2);
                *(float2*)&stO[gb] = make_float2(hnv[0], hnv[1]);
                if (colg < 22) *(float2*)&stO[gb + 2] = make_float2(hnv[2], hnv[3]);
            }
        };

        // ---- seg 0: mm chunk 0 | setup ----
        if (mm) MM_CHUNK(0, 13)
        else if (hp) {
            if (hw == 0) {
                for (int m = hl; m < Hc; m += 64) ss_s[m] = stIn[((size_t)(bb * KUc + q)) * Hc + m];
                for (int m = hl; m < Hc; m += 64) ceq_s[m] = concept_emb[q * Hc + m];
            } else if (hw == 1) {
                int r = hl, k = k0 + r;
                float nv = nb_adj[(size_t)q * KUc + k];
                float sv = succ_adj[(size_t)q * KUc + k];
                nbv_s[r] = nv; sv_s[r] = sv;
                bool act = (nv != 0.0f) || (sv != 0.0f) || (k == q);
                unsigned long long mb = __ballot(act);
                int rank = __popcll(mb & ((1ull << hl) - 1ull));
                rowslot[r] = act ? (1 + rank) : 0;
                if (act) list_s[rank] = r;
                if (hl == 0) cnt_s[0] = (int)__popcll(mb);
            } else if (hw == 2) {
                if (owner) {
                    int base = 0;
                    for (int ch = 0; ch < 8; ++ch) {
                        int kp = ch * 64 + hl;
                        float nv = nb_adj[(size_t)q * KUc + kp];
                        unsigned long long mb = __ballot(nv != 0.0f);
                        int idx = base + (int)__popcll(mb & ((1ull << hl) - 1ull));
                        if (nv != 0.0f && idx < NBCAP) nblist[idx] = kp;
                        base += (int)__popcll(mb);
                    }
                    if (hl == 0) cnt_s[1] = (base < NBCAP) ? base : NBCAP;
                }
            } else if (hw == 3) {
                for (int i = hl; i < NHW * 92; i += 64) ((float*)reflp)[i] = 0.0f;
            }
        }
        __syncthreads();

        // ---- seg 1: mm chunk 1 | self-GRU matvecs ----
        if (mm) MM_CHUNK(13, 26)
        else if (hp) {
            for (int i = hidx; i < 2 * H3c; i += 320) {
                if (i < H3c) {
                    float acc = bi_self[i];
                    for (int kk = 0; kk < Hc; ++kk)
                        acc += response_emb[(size_t)a * Hc + kk] * Wi_self[kk * H3c + i];
                    gia[i] = acc;
                } else {
                    int c = i - H3c;
                    float acc = bh_self[c];
                    for (int kk = 0; kk < Hc; ++kk)
                        acc += ss_s[kk] * Wh_self[kk * H3c + c];
                    gha[c] = acc;
                }
            }
        }
        __syncthreads();

        // ---- seg 2: mm chunk 2 | self-GRU gates ----
        if (mm) MM_CHUNK(26, 39)
        else if (hp && hidx < Hc) {
            int m = hidx;
            float r = sigf(gia[m] + gha[m]);
            float z = sigf(gia[Hc + m] + gha[Hc + m]);
            float g = tanhf_(gia[2 * Hc + m] + r * gha[2 * Hc + m]);
            ns_s[m] = (1.0f - z) * g + z * ss_s[m];
        }
        __syncthreads();

        // ---- seg 3: mm chunk 3 | nsync + pvec ----
        if (mm) MM_CHUNK(39, 52)
        else if (hp) {
            if (hidx < Hc) {
                int m = hidx;
                float acc = 0.0f;
                for (int kk = 0; kk < Hc; ++kk) acc += ns_s[kk] * W_sync[(Hc + kk) * Hc + m];
                nsync_s[m] = acc;
            } else if (hidx < 2 * Hc) {
                int m = hidx - Hc;
                float acc = b_prop[m];
                for (int kk = 0; kk < Hc; ++kk) acc += (ns_s[kk] - ss_s[kk]) * W_prop[kk * Hc + m];
                for (int kk = 0; kk < Hc; ++kk) acc += ceq_s[kk] * W_prop[(Hc + kk) * Hc + m];
                pvec_s[m] = fmaxf(acc, 0.0f);
            }
        }
        __syncthreads();

        // ---- seg 4: mm chunk 4 | reflec partials (owner) ----
        if (mm) MM_CHUNK(52, 65)
        else if (hp && owner) {
            int nnb = cnt_s[1];
            for (int j = hw; j < nnb; j += NHW) {
                int kp = nblist[j];
                float nv = nb_adj[(size_t)q * KUc + kp];
                const float* hpold = &stIn[((size_t)(bb * KUc + kp)) * Hc];
#pragma unroll
                for (int mb = 0; mb < 2; ++mb) {
                    int m = mb * 64 + hl;
                    if (m < Hc) {
                        float acc = nsync_s[m] + ce_ws[(size_t)kp * Hc + m];
                        for (int kk = 0; kk < Hc; ++kk)
                            acc += hpold[kk] * W_sync[kk * Hc + m];
                        reflp[hw][m] += nv * fmaxf(acc, 0.0f);
                    }
                }
            }
        }
        __syncthreads();

        // ---- seg 5: mm chunk 5 | reflec reduce + non-q chains (batch 0) ----
        if (mm) MM_CHUNK(65, 78)
        else if (hp) {
            if (hidx < Hc)
                reflec_s[hidx] = reflp[0][hidx] + reflp[1][hidx] + reflp[2][hidx] +
                                 reflp[3][hidx] + reflp[4][hidx];
            chainRows(0, 0);
        }
        __syncthreads();

        // ---- seg 6: mm chunk 6 | q-row chain (batch 0) ----
        if (mm) MM_CHUNK(78, 90)
        else if (hp && owner) {
            chainRows(0, 1);
        }
        __syncthreads();

        // ---- apply pass 0 ----
        if (mm) applyPass(0, stOut);
        __syncthreads();

        // ---- rare extra batches ----
        {
            int nact_v = cnt_s[0];
            for (int p = 1; p * BSLOT < nact_v; ++p) {
                if (hp) chainRows(p, 2);
                __syncthreads();
                if (mm) applyPass(p, stOut);
                __syncthreads();
            }
        }

        // ---- seg 8: predictions + counter reset ----
        if (hp && hidx < ROWSc) {
            int r = hidx;
            float acc = bout_s;
            for (int m = 0; m < Hc; ++m) acc += h_sT[hadr(m, r)] * wout_s[m];
            out[(size_t)t * Bc * KUc + (size_t)bb * KUc + k0 + r] = sigf(acc);
        }
        if (tid == BLKT - 1) { cnt_s[0] = 0; cnt_s[1] = 0; }

        gridbar(bar, 2 + t);
    }
}

extern "C" void kernel_launch(void* const* d_in, const int* in_sizes, int n_in,
                              void* d_out, int out_size, void* d_ws, size_t ws_size,
                              hipStream_t stream) {
    const int* questions = (const int*)d_in[0];
    const int* answers = (const int*)d_in[1];
    const float* response_emb = (const float*)d_in[2];
    const float* concept_emb = (const float*)d_in[3];
    const float* nb_adj = (const float*)d_in[4];
    const float* succ_adj = (const float*)d_in[5];
    const float* Wi_self = (const float*)d_in[6];
    const float* Wh_self = (const float*)d_in[7];
    const float* bi_self = (const float*)d_in[8];
    const float* bh_self = (const float*)d_in[9];
    const float* Wi_rnn = (const float*)d_in[10];
    const float* Wh_rnn = (const float*)d_in[11];
    const float* bi_rnn = (const float*)d_in[12];
    const float* bh_rnn = (const float*)d_in[13];
    const float* W_sync = (const float*)d_in[14];
    const float* b_sync = (const float*)d_in[15];
    const float* W_prop = (const float*)d_in[16];
    const float* b_prop = (const float*)d_in[17];
    const float* W_agg = (const float*)d_in[18];
    const float* b_agg = (const float*)d_in[19];
    const float* W_out = (const float*)d_in[20];
    const float* b_out = (const float*)d_in[21];

    float* out = (float*)d_out;
    float* stA = out + (size_t)Tc * Bc * KUc;           // final-states region of d_out
    unsigned* bar = (unsigned*)d_ws;
    float* ce_ws = (float*)d_ws + 64;
    float* stB = ce_ws + (size_t)KUc * Hc;

    hipMemsetAsync(d_ws, 0, 256, stream);                                   // barrier state
    hipMemsetAsync(stA, 0, (size_t)Bc * KUc * Hc * sizeof(float), stream);  // initial states

    void* args[] = {
        (void*)&questions, (void*)&answers, (void*)&response_emb, (void*)&concept_emb,
        (void*)&nb_adj, (void*)&succ_adj, (void*)&Wi_self, (void*)&Wh_self,
        (void*)&bi_self, (void*)&bh_self, (void*)&Wi_rnn, (void*)&Wh_rnn,
        (void*)&bi_rnn, (void*)&bh_rnn, (void*)&W_sync, (void*)&b_sync,
        (void*)&W_prop, (void*)&b_prop, (void*)&W_agg, (void*)&b_agg,
        (void*)&W_out, (void*)&b_out, (void*)&out, (void*)&stA, (void*)&stB,
        (void*)&ce_ws, (void*)&bar};
    hipError_t e = hipLaunchCooperativeKernel((const void*)skt_persist, dim3(NBLK),
                                              dim3(BLKT), args, 0, stream);
    if (e != hipSuccess) {
        skt_persist<<<NBLK, BLKT, 0, stream>>>(
            questions, answers, response_emb, concept_emb, nb_adj, succ_adj,
            Wi_self, Wh_self, bi_self, bh_self, Wi_rnn, Wh_rnn, bi_rnn, bh_rnn,
            W_sync, b_sync, W_prop, b_prop, W_agg, b_agg, W_out, b_out,
            out, stA, stB, ce_ws, bar);
    }
}

// Round 3
// 6564.664 us; speedup vs baseline: 10.8041x; 10.8041x over previous
//
#include <hip/hip_runtime.h>

#define KU 512
#define NB 32
#define NT 64
#define H_ 90
#define HP 92
#define H3 270
#define WHP 292
#define TILE 64
#define SLOTS 20
#define NBMAX 40

// ---- ws float offsets ----
#define OFF_PONG  0
#define N_PONG    (KU * NB * H_)                 // 1474560
#define OFF_WHP   (N_PONG)
#define OFF_SYLO  (OFF_WHP + 90 * WHP)
#define OFF_SYMID (OFF_SYLO + 90 * HP)
#define OFF_AGG   (OFF_SYMID + 90 * HP)
#define OFF_WIR   (OFF_AGG + 90 * HP)
#define OFF_WPR   (OFF_WIR + H3 * HP)
#define OFF_WIS   (OFF_WPR + 90 * 180)
#define OFF_WHS   (OFF_WIS + H3 * HP)
#define OFF_CEB   (OFF_WHS + H3 * HP)
#define OFF_GI0   (OFF_CEB + KU * 90)
#define OFF_ABUF  (OFF_GI0 + 272)

__device__ __forceinline__ float sigf(float x) { return 1.0f / (1.0f + __expf(-x)); }
__device__ __forceinline__ float tanhf_(float x) {
    float e = __expf(2.0f * x);
    return 1.0f - 2.0f / (e + 1.0f);
}
__device__ __forceinline__ float dot4(float4 a, float4 b) {
    return a.x * b.x + a.y * b.y + a.z * b.z + a.w * b.w;
}
#define WAVE_SYNC() { asm volatile("s_waitcnt lgkmcnt(0)" ::: "memory"); __builtin_amdgcn_sched_barrier(0); }

// ============ prep: transposed weights + ce_sync + gi0 (once per call) ============
__global__ void skt_prep(const float* __restrict__ concept_emb, const float* __restrict__ W_sync,
                         const float* __restrict__ b_sync, const float* __restrict__ W_agg,
                         const float* __restrict__ W_prop, const float* __restrict__ Wi_rnn,
                         const float* __restrict__ Wh_rnn, const float* __restrict__ Wi_self,
                         const float* __restrict__ Wh_self, const float* __restrict__ bi_rnn,
                         const float* __restrict__ b_agg, float* __restrict__ ws) {
    const int blk = blockIdx.x, tid = threadIdx.x;
    if (blk < 128) {                       // ce_syncB[512][90] = b_sync + ce@W_sync[180:270]
        for (int rr = 0; rr < 4; ++rr) {
            const int k = blk * 4 + rr;
            if (tid < 90) {
                float acc = b_sync[tid];
                for (int kk = 0; kk < 90; ++kk)
                    acc += concept_emb[k * 90 + kk] * W_sync[(180 + kk) * 90 + tid];
                ws[OFF_CEB + k * 90 + tid] = acc;
            }
        }
    } else if (blk < 137) {                // WisT[270][92]
        const int c0 = (blk - 128) * 30;
        for (int rr = 0; rr < 30; ++rr) {
            const int c = c0 + rr;
            if (tid < 92) ws[OFF_WIS + c * 92 + tid] = (tid < 90) ? Wi_self[tid * 270 + c] : 0.f;
        }
    } else if (blk < 146) {                // WhsT[270][92]
        const int c0 = (blk - 137) * 30;
        for (int rr = 0; rr < 30; ++rr) {
            const int c = c0 + rr;
            if (tid < 92) ws[OFF_WHS + c * 92 + tid] = (tid < 90) ? Wh_self[tid * 270 + c] : 0.f;
        }
    } else if (blk < 155) {                // WirT[270][92]
        const int c0 = (blk - 146) * 30;
        for (int rr = 0; rr < 30; ++rr) {
            const int c = c0 + rr;
            if (tid < 92) ws[OFF_WIR + c * 92 + tid] = (tid < 90) ? Wi_rnn[tid * 270 + c] : 0.f;
        }
    } else if (blk < 158) {                // WsyT_lo[90][92]
        const int m0 = (blk - 155) * 30;
        for (int rr = 0; rr < 30; ++rr) {
            const int m = m0 + rr;
            if (tid < 92) ws[OFF_SYLO + m * 92 + tid] = (tid < 90) ? W_sync[tid * 90 + m] : 0.f;
        }
    } else if (blk < 161) {                // WsyT_mid[90][92]
        const int m0 = (blk - 158) * 30;
        for (int rr = 0; rr < 30; ++rr) {
            const int m = m0 + rr;
            if (tid < 92) ws[OFF_SYMID + m * 92 + tid] = (tid < 90) ? W_sync[(90 + tid) * 90 + m] : 0.f;
        }
    } else if (blk < 164) {                // WaggT[90][92]
        const int m0 = (blk - 161) * 30;
        for (int rr = 0; rr < 30; ++rr) {
            const int m = m0 + rr;
            if (tid < 92) ws[OFF_AGG + m * 92 + tid] = (tid < 90) ? W_agg[tid * 90 + m] : 0.f;
        }
    } else if (blk < 167) {                // WprT[90][180]
        const int m0 = (blk - 164) * 30;
        for (int rr = 0; rr < 30; ++rr) {
            const int m = m0 + rr;
            if (tid < 180) ws[OFF_WPR + m * 180 + tid] = W_prop[tid * 90 + m];
        }
    } else if (blk < 176) {                // WhP[90][292]
        const int k0 = (blk - 167) * 10;
        for (int rr = 0; rr < 10; ++rr) {
            const int k = k0 + rr;
            for (int c = tid; c < 292; c += 256)
                ws[OFF_WHP + k * 292 + c] = (c < 270) ? Wh_rnn[k * 270 + c] : 0.f;
        }
    } else if (blk == 176) {               // gi0[272] = bi_rnn + relu(b_agg)@Wi_rnn
        for (int c = tid; c < 272; c += 256) {
            float acc = 0.f;
            if (c < 270) {
                acc = bi_rnn[c];
                for (int kk = 0; kk < 90; ++kk)
                    acc += fmaxf(b_agg[kk], 0.f) * Wi_rnn[kk * 270 + c];
            }
            ws[OFF_GI0 + c] = acc;
        }
    }
}

// ============ K1: per-batch scalars (self GRU, nsync, pvec, reflec) ============
__global__ __launch_bounds__(320, 1) void skt_batch(
    const int* __restrict__ qs, const int* __restrict__ as_,
    const float* __restrict__ response_emb, const float* __restrict__ concept_emb,
    const float* __restrict__ nb_adj, const float* __restrict__ bi_self,
    const float* __restrict__ bh_self, const float* __restrict__ b_prop,
    float* __restrict__ ws, const float* __restrict__ stIn, int t) {
    __shared__ alignas(16) float re[92], ssv[92], ceq[92], nsv[92], xprop[180];
    __shared__ alignas(16) float giA[272], ghA[272];
    __shared__ alignas(16) float nsyL[92];
    __shared__ alignas(16) float hnb[NBMAX][92];
    __shared__ float nbw[NBMAX];
    __shared__ int nblist[NBMAX];
    __shared__ int nnbS;

    const int tid = threadIdx.x;
    const int b = blockIdx.x;
    const int q = qs[b * NT + t], a = as_[b * NT + t];

    if (tid < 90) {
        re[tid] = response_emb[(size_t)a * 90 + tid];
        ssv[tid] = stIn[((size_t)(b * KU + q)) * 90 + tid];
        ceq[tid] = concept_emb[(size_t)q * 90 + tid];
    } else if (tid < 92) {
        re[tid] = 0.f; ssv[tid] = 0.f; ceq[tid] = 0.f;
    }
    if (tid < 64) {                         // neighbor scan (wave 0)
        int base = 0;
        for (int ch = 0; ch < 8; ++ch) {
            const int kp = ch * 64 + tid;
            const float nv = nb_adj[(size_t)q * KU + kp];
            const unsigned long long mb = __ballot(nv != 0.f);
            const int idx = base + (int)__popcll(mb & ((1ull << tid) - 1ull));
            if (nv != 0.f && idx < NBMAX) { nblist[idx] = kp; nbw[idx] = nv; }
            base += (int)__popcll(mb);
        }
        if (tid == 0) nnbS = (base < NBMAX) ? base : NBMAX;
    }
    __syncthreads();
    if (tid < 270) {                        // self-GRU matvecs (streamed WT rows)
        float a1 = bi_self[tid], a2 = bh_self[tid];
        const float4* w1 = (const float4*)(ws + OFF_WIS + (size_t)tid * 92);
        const float4* w2 = (const float4*)(ws + OFF_WHS + (size_t)tid * 92);
        const float4* rv = (const float4*)re;
        const float4* sv4 = (const float4*)ssv;
#pragma unroll 4
        for (int p = 0; p < 23; ++p) { a1 += dot4(rv[p], w1[p]); a2 += dot4(sv4[p], w2[p]); }
        giA[tid] = a1; ghA[tid] = a2;
    }
    __syncthreads();
    if (tid < 90) {                         // next_self
        const float r = sigf(giA[tid] + ghA[tid]);
        const float z = sigf(giA[90 + tid] + ghA[90 + tid]);
        const float g = tanhf_(giA[180 + tid] + r * ghA[180 + tid]);
        nsv[tid] = (1.f - z) * g + z * ssv[tid];
    } else if (tid < 92) nsv[tid] = 0.f;
    __syncthreads();
    if (tid < 90) {                         // nsync + xprop
        const float4* wm = (const float4*)(ws + OFF_SYMID + (size_t)tid * 92);
        const float4* nv4 = (const float4*)nsv;
        float d = 0.f;
#pragma unroll 4
        for (int p = 0; p < 23; ++p) d += dot4(nv4[p], wm[p]);
        nsyL[tid] = d;
        xprop[tid] = nsv[tid] - ssv[tid];
        xprop[90 + tid] = ceq[tid];
    }
    {                                       // stage neighbor states (all threads)
        const int nnb = nnbS;
        const int nnb4 = (nnb + 3) & ~3;
        for (int i = tid; i < nnb4 * 92; i += 320) {
            const int j = i / 92, c = i - j * 92;
            hnb[j][c] = (j < nnb && c < 90) ? stIn[((size_t)(b * KU + nblist[j])) * 90 + c] : 0.f;
        }
    }
    __syncthreads();
    if (tid < 90) {                         // pvec + reflec + ABUF writes
        const int m = tid;
        const float4* wp = (const float4*)(ws + OFF_WPR + (size_t)m * 180);
        const float4* xp = (const float4*)xprop;
        float d = b_prop[m];
#pragma unroll 5
        for (int p = 0; p < 45; ++p) d += dot4(xp[p], wp[p]);
        const float pv = fmaxf(d, 0.f);

        float racc = 0.f;
        const int nnb = nnbS;
        const int nnb4 = (nnb + 3) & ~3;
        const float4* wrow = (const float4*)(ws + OFF_SYLO + (size_t)m * 92);
        const float nsym = nsyL[m];
        for (int j0 = 0; j0 < nnb4; j0 += 4) {
            float a0 = 0.f, a1 = 0.f, a2 = 0.f, a3 = 0.f;
#pragma unroll 4
            for (int p = 0; p < 23; ++p) {
                const float4 w = wrow[p];
                a0 += dot4(((const float4*)&hnb[j0 + 0][0])[p], w);
                a1 += dot4(((const float4*)&hnb[j0 + 1][0])[p], w);
                a2 += dot4(((const float4*)&hnb[j0 + 2][0])[p], w);
                a3 += dot4(((const float4*)&hnb[j0 + 3][0])[p], w);
            }
            const float aj[4] = {a0, a1, a2, a3};
#pragma unroll
            for (int jj = 0; jj < 4; ++jj) {
                const int j = j0 + jj;
                if (j < nnb)
                    racc += nbw[j] * fmaxf(nsym + ws[OFF_CEB + (size_t)nblist[j] * 90 + m] + aj[jj], 0.f);
            }
        }
        ws[OFF_ABUF + (size_t)b * 92 + m] = nsym;
        ws[OFF_ABUF + (size_t)(32 + b) * 92 + m] = pv;
        ws[OFF_ABUF + (size_t)(64 + b) * 92 + m] = racc;
    }
}

// ============ K2: 64-row tile — GEMM (waves 0-5) ∥ chains (waves 6-7) → gates → out ============
__global__ __launch_bounds__(512, 1) void skt_tile(
    const int* __restrict__ qs, const float* __restrict__ nb_adj,
    const float* __restrict__ succ_adj, const float* __restrict__ bi_rnn,
    const float* __restrict__ bh_rnn, const float* __restrict__ b_agg,
    const float* __restrict__ W_out, const float* __restrict__ b_out,
    float* __restrict__ ws, const float* __restrict__ stIn, float* __restrict__ stOut,
    float* __restrict__ out, int t) {
    __shared__ alignas(16) float big[90 * WHP];          // Wh staged; reused as gh[64][292]
    __shared__ alignas(16) float hL[TILE * 92];
    __shared__ alignas(16) float giL[SLOTS * 273];
    __shared__ alignas(16) float gi0L[272], biL[272], bhL[292];
    __shared__ alignas(16) float baggL[92], nsyL[92], pvL[92], rfL[92], woutL[92];
    __shared__ alignas(16) float actb[2][92], infb[2][92];
    __shared__ float nbvL[TILE], svL[TILE];
    __shared__ int rowslotS[TILE], listS[TILE];
    __shared__ int nactS;

    const int tid = threadIdx.x;
    const int bb = blockIdx.x >> 3;
    const int k0 = (blockIdx.x & 7) * TILE;
    const int q = qs[bb * NT + t];

    // ---------- phase S: stage ----------
    if (tid < 384) {
        for (int i = tid; i < 90 * 73; i += 384)
            ((float4*)big)[i] = ((const float4*)(ws + OFF_WHP))[i];
        for (int i = tid; i < TILE * 45; i += 384) {
            const int r = i / 45, c2 = i - r * 45;
            const float2 v = ((const float2*)(stIn + ((size_t)(bb * KU + k0 + r)) * 90))[c2];
            hL[r * 92 + c2 * 2] = v.x;
            hL[r * 92 + c2 * 2 + 1] = v.y;
        }
    } else if (tid < 448) {
        const int lane = tid - 384;
        const int kg = k0 + lane;
        const float nv = nb_adj[(size_t)q * KU + kg];
        const float sv = succ_adj[(size_t)q * KU + kg];
        nbvL[lane] = nv; svL[lane] = sv;
        const bool act = (nv != 0.f) || (sv != 0.f) || (kg == q);
        const unsigned long long mb = __ballot(act);
        const int rank = (int)__popcll(mb & ((1ull << lane) - 1ull));
        rowslotS[lane] = (act && rank < SLOTS) ? rank : -1;
        if (act && rank < SLOTS) listS[rank] = lane;
        if (lane == 0) nactS = min((int)__popcll(mb), SLOTS);
        for (int i = lane; i < 128; i += 64) hL[(i >> 1) * 92 + 90 + (i & 1)] = 0.f;
        if (lane < 2) { actb[0][90 + lane] = 0.f; actb[1][90 + lane] = 0.f;
                        infb[0][90 + lane] = 0.f; infb[1][90 + lane] = 0.f; }
    } else {
        const int lane = tid - 448;
        for (int c = lane; c < 272; c += 64) {
            gi0L[c] = ws[OFF_GI0 + c];
            biL[c] = (c < 270) ? bi_rnn[c] : 0.f;
        }
        for (int c = lane; c < 292; c += 64) bhL[c] = (c < 270) ? bh_rnn[c] : 0.f;
        for (int m = lane; m < 90; m += 64) {
            baggL[m] = b_agg[m];
            nsyL[m] = ws[OFF_ABUF + (size_t)bb * 92 + m];
            pvL[m]  = ws[OFF_ABUF + (size_t)(32 + bb) * 92 + m];
            rfL[m]  = ws[OFF_ABUF + (size_t)(64 + bb) * 92 + m];
            woutL[m] = W_out[m];
        }
    }
    __syncthreads();   // #1

    // ---------- GEMM ∥ chains ----------
    float acc[4][12];
    int rg = 0, cg = 0;
    if (tid < 384) {
        rg = tid / 24; cg = tid - rg * 24;
#pragma unroll
        for (int rr = 0; rr < 4; ++rr)
#pragma unroll
            for (int j = 0; j < 12; ++j) acc[rr][j] = 0.f;
        const int r0 = rg * 4;
#pragma unroll 2
        for (int k = 0; k < 90; ++k) {
            const float h0 = hL[(r0 + 0) * 92 + k];
            const float h1 = hL[(r0 + 1) * 92 + k];
            const float h2 = hL[(r0 + 2) * 92 + k];
            const float h3 = hL[(r0 + 3) * 92 + k];
            const float4* wp = (const float4*)&big[k * WHP + cg * 12];
            const float4 w0 = wp[0], w1 = wp[1], w2 = wp[2];
            const float wv[12] = {w0.x, w0.y, w0.z, w0.w, w1.x, w1.y, w1.z, w1.w,
                                  w2.x, w2.y, w2.z, w2.w};
#pragma unroll
            for (int j = 0; j < 12; ++j) {
                const float w = wv[j];
                acc[0][j] += h0 * w; acc[1][j] += h1 * w;
                acc[2][j] += h2 * w; acc[3][j] += h3 * w;
            }
        }
    } else {
        const int w2 = (tid >> 6) - 6;     // 0 or 1
        const int lane = tid & 63;
        const int nact = nactS;
        for (int e = w2; e < nact; e += 2) {
            const int r = listS[e];
            const float nv = nbvL[r], sv = svL[r];
            const bool isq = (k0 + r == q);
            for (int m = lane; m < 90; m += 64) {
                float sy = 0.f;
                if (nv != 0.f) {
                    float a0 = nsyL[m] + ws[OFF_CEB + (size_t)(k0 + r) * 90 + m];
                    const float4* wrow = (const float4*)(ws + OFF_SYLO + (size_t)m * 92);
                    const float4* hr4 = (const float4*)&hL[r * 92];
                    float d = 0.f;
#pragma unroll 4
                    for (int p = 0; p < 23; ++p) d += dot4(hr4[p], wrow[p]);
                    sy = nv * fmaxf(a0 + d, 0.f);
                }
                if (isq) sy += rfL[m];
                actb[w2][m] = 0.5f * sy + 0.5f * sv * pvL[m];
            }
            WAVE_SYNC();
            for (int m = lane; m < 90; m += 64) {
                const float4* wrow = (const float4*)(ws + OFF_AGG + (size_t)m * 92);
                const float4* av = (const float4*)&actb[w2][0];
                float d = baggL[m];
#pragma unroll 4
                for (int p = 0; p < 23; ++p) d += dot4(av[p], wrow[p]);
                infb[w2][m] = fmaxf(d, 0.f);
            }
            WAVE_SYNC();
            for (int c = lane; c < 270; c += 64) {
                const float4* wrow = (const float4*)(ws + OFF_WIR + (size_t)c * 92);
                const float4* iv = (const float4*)&infb[w2][0];
                float d = biL[c];
#pragma unroll 4
                for (int p = 0; p < 23; ++p) d += dot4(iv[p], wrow[p]);
                giL[e * 273 + c] = d;
            }
            WAVE_SYNC();
        }
    }
    __syncthreads();   // #2 — GEMM reads of big done everywhere

    if (tid < 384) {   // write gh = acc + bh into big (alias)
#pragma unroll
        for (int rr = 0; rr < 4; ++rr) {
            const int row = rg * 4 + rr;
#pragma unroll
            for (int j = 0; j < 12; ++j)
                big[row * WHP + cg * 12 + j] = acc[rr][j] + bhL[cg * 12 + j];
        }
    }
    __syncthreads();   // #3

    // ---------- gates ----------
    for (int i = tid; i < TILE * 90; i += 512) {
        const int row = i / 90;
        const int m = i - row * 90;
        const int slot = rowslotS[row];
        const float* gsrc = (slot >= 0) ? &giL[slot * 273] : gi0L;
        const float hr_ = big[row * WHP + m];
        const float hz_ = big[row * WHP + 90 + m];
        const float hg_ = big[row * WHP + 180 + m];
        const float r = sigf(gsrc[m] + hr_);
        const float z = sigf(gsrc[90 + m] + hz_);
        const float g = tanhf_(gsrc[180 + m] + r * hg_);
        const float hn = (1.f - z) * g + z * hL[row * 92 + m];
        hL[row * 92 + m] = hn;
        stOut[((size_t)(bb * KU + k0 + row)) * 90 + m] = hn;
    }
    __syncthreads();   // #4

    // ---------- out head ----------
    if (tid < TILE) {
        float a0 = b_out[0];
        for (int m = 0; m < 90; ++m) a0 += hL[tid * 92 + m] * woutL[m];
        out[(size_t)t * NB * KU + (size_t)bb * KU + k0 + tid] = sigf(a0);
    }
}

extern "C" void kernel_launch(void* const* d_in, const int* in_sizes, int n_in,
                              void* d_out, int out_size, void* d_ws, size_t ws_size,
                              hipStream_t stream) {
    const int* questions = (const int*)d_in[0];
    const int* answers = (const int*)d_in[1];
    const float* response_emb = (const float*)d_in[2];
    const float* concept_emb = (const float*)d_in[3];
    const float* nb_adj = (const float*)d_in[4];
    const float* succ_adj = (const float*)d_in[5];
    const float* Wi_self = (const float*)d_in[6];
    const float* Wh_self = (const float*)d_in[7];
    const float* bi_self = (const float*)d_in[8];
    const float* bh_self = (const float*)d_in[9];
    const float* Wi_rnn = (const float*)d_in[10];
    const float* Wh_rnn = (const float*)d_in[11];
    const float* bi_rnn = (const float*)d_in[12];
    const float* bh_rnn = (const float*)d_in[13];
    const float* W_sync = (const float*)d_in[14];
    const float* b_sync = (const float*)d_in[15];
    const float* W_prop = (const float*)d_in[16];
    const float* b_prop = (const float*)d_in[17];
    const float* W_agg = (const float*)d_in[18];
    const float* b_agg = (const float*)d_in[19];
    const float* W_out = (const float*)d_in[20];
    const float* b_out = (const float*)d_in[21];

    float* out = (float*)d_out;
    float* stFinal = out + (size_t)NT * NB * KU;   // states region of d_out
    float* ws = (float*)d_ws;

    hipMemsetAsync(stFinal, 0, (size_t)NB * KU * H_ * sizeof(float), stream);
    skt_prep<<<177, 256, 0, stream>>>(concept_emb, W_sync, b_sync, W_agg, W_prop, Wi_rnn,
                                      Wh_rnn, Wi_self, Wh_self, bi_rnn, b_agg, ws);
    for (int t = 0; t < NT; ++t) {
        const float* sin = (t & 1) ? (ws + OFF_PONG) : stFinal;
        float* sout = (t & 1) ? stFinal : (ws + OFF_PONG);
        skt_batch<<<NB, 320, 0, stream>>>(questions, answers, response_emb, concept_emb,
                                          nb_adj, bi_self, bh_self, b_prop, ws, sin, t);
        skt_tile<<<NB * 8, 512, 0, stream>>>(questions, nb_adj, succ_adj, bi_rnn, bh_rnn,
                                             b_agg, W_out, b_out, ws, sin, sout, out, t);
    }
}

// Round 4
// 5107.795 us; speedup vs baseline: 13.8857x; 1.2852x over previous
//
#include <hip/hip_runtime.h>

#define KU 512
#define NB 32
#define NT 64
#define TIL 32
#define SLOTS 12
#define NBMAX 40

// ---- ws float offsets ----
#define N_PONG   (KU * NB * 90)
#define OFF_WHB  (N_PONG)                      // [3][90][92] gate-major Wh_rnn
#define OFF_SYLO (OFF_WHB + 3 * 90 * 92)       // W_sync[0:90]^T   [90][92]
#define OFF_SYMID (OFF_SYLO + 90 * 92)         // W_sync[90:180]^T [90][92]
#define OFF_AGG  (OFF_SYMID + 90 * 92)         // W_agg^T          [90][92]
#define OFF_WIR  (OFF_AGG + 90 * 92)           // Wi_rnn^T         [270][92]
#define OFF_WPR  (OFF_WIR + 270 * 92)          // W_prop^T         [90][180]
#define OFF_WIS  (OFF_WPR + 90 * 180)          // Wi_self^T        [270][92]
#define OFF_WHS  (OFF_WIS + 270 * 92)          // Wh_self^T        [270][92]
#define OFF_CEB  (OFF_WHS + 270 * 92)          // ce_sync+b_sync   [512][90]
#define OFF_GI0  (OFF_CEB + KU * 90)           // gi0 [272]
#define OFF_ABUF (OFF_GI0 + 272)               // [96][92]: nsy | pvec | reflec per batch

struct __attribute__((aligned(4))) f3v { float x, y, z; };

__device__ __forceinline__ float sigf(float x) { return 1.0f / (1.0f + __expf(-x)); }
__device__ __forceinline__ float tanhf_(float x) {
    float e = __expf(2.0f * x);
    return 1.0f - 2.0f / (e + 1.0f);
}
__device__ __forceinline__ float dot4(float4 a, float4 b) {
    return a.x * b.x + a.y * b.y + a.z * b.z + a.w * b.w;
}
#define WAVE_SYNC() { asm volatile("s_waitcnt lgkmcnt(0)" ::: "memory"); __builtin_amdgcn_sched_barrier(0); }

// ============ prep: transposed/padded weights + ce_sync + gi0 ============
__global__ void skt_prep(const float* __restrict__ concept_emb, const float* __restrict__ W_sync,
                         const float* __restrict__ b_sync, const float* __restrict__ W_agg,
                         const float* __restrict__ W_prop, const float* __restrict__ Wi_rnn,
                         const float* __restrict__ Wh_rnn, const float* __restrict__ Wi_self,
                         const float* __restrict__ Wh_self, const float* __restrict__ bi_rnn,
                         const float* __restrict__ b_agg, float* __restrict__ ws) {
    const int blk = blockIdx.x, tid = threadIdx.x;
    if (blk < 128) {                       // ce_syncB[512][90]
        for (int rr = 0; rr < 4; ++rr) {
            const int k = blk * 4 + rr;
            if (tid < 90) {
                float acc = b_sync[tid];
                for (int kk = 0; kk < 90; ++kk)
                    acc += concept_emb[k * 90 + kk] * W_sync[(180 + kk) * 90 + tid];
                ws[OFF_CEB + k * 90 + tid] = acc;
            }
        }
    } else if (blk < 137) {                // WisT[270][92]
        const int c0 = (blk - 128) * 30;
        for (int rr = 0; rr < 30; ++rr) {
            const int c = c0 + rr;
            if (tid < 92) ws[OFF_WIS + c * 92 + tid] = (tid < 90) ? Wi_self[tid * 270 + c] : 0.f;
        }
    } else if (blk < 146) {                // WhsT[270][92]
        const int c0 = (blk - 137) * 30;
        for (int rr = 0; rr < 30; ++rr) {
            const int c = c0 + rr;
            if (tid < 92) ws[OFF_WHS + c * 92 + tid] = (tid < 90) ? Wh_self[tid * 270 + c] : 0.f;
        }
    } else if (blk < 155) {                // WirT[270][92]
        const int c0 = (blk - 146) * 30;
        for (int rr = 0; rr < 30; ++rr) {
            const int c = c0 + rr;
            if (tid < 92) ws[OFF_WIR + c * 92 + tid] = (tid < 90) ? Wi_rnn[tid * 270 + c] : 0.f;
        }
    } else if (blk < 158) {                // WsyT_lo[90][92]
        const int m0 = (blk - 155) * 30;
        for (int rr = 0; rr < 30; ++rr) {
            const int m = m0 + rr;
            if (tid < 92) ws[OFF_SYLO + m * 92 + tid] = (tid < 90) ? W_sync[tid * 90 + m] : 0.f;
        }
    } else if (blk < 161) {                // WsyT_mid[90][92]
        const int m0 = (blk - 158) * 30;
        for (int rr = 0; rr < 30; ++rr) {
            const int m = m0 + rr;
            if (tid < 92) ws[OFF_SYMID + m * 92 + tid] = (tid < 90) ? W_sync[(90 + tid) * 90 + m] : 0.f;
        }
    } else if (blk < 164) {                // WaggT[90][92]
        const int m0 = (blk - 161) * 30;
        for (int rr = 0; rr < 30; ++rr) {
            const int m = m0 + rr;
            if (tid < 92) ws[OFF_AGG + m * 92 + tid] = (tid < 90) ? W_agg[tid * 90 + m] : 0.f;
        }
    } else if (blk < 167) {                // WprT[90][180]
        const int m0 = (blk - 164) * 30;
        for (int rr = 0; rr < 30; ++rr) {
            const int m = m0 + rr;
            if (tid < 180) ws[OFF_WPR + m * 180 + tid] = W_prop[tid * 90 + m];
        }
    } else if (blk < 176) {                // WhB[3][90][92] gate-major
        const int k0 = (blk - 167) * 10;
        for (int rr = 0; rr < 10; ++rr) {
            const int k = k0 + rr;
            for (int i = tid; i < 276; i += 256) {
                const int g = i / 92, m = i - g * 92;
                ws[OFF_WHB + (size_t)g * 90 * 92 + k * 92 + m] =
                    (m < 90) ? Wh_rnn[k * 270 + g * 90 + m] : 0.f;
            }
        }
    } else if (blk == 176) {               // gi0[272]
        for (int c = tid; c < 272; c += 256) {
            float acc = 0.f;
            if (c < 270) {
                acc = bi_rnn[c];
                for (int kk = 0; kk < 90; ++kk)
                    acc += fmaxf(b_agg[kk], 0.f) * Wi_rnn[kk * 270 + c];
            }
            ws[OFF_GI0 + c] = acc;
        }
    }
}

// ============ K1: per-batch self GRU, nsync, pvec, reflec ============
__global__ __launch_bounds__(320, 1) void skt_batch(
    const int* __restrict__ qs, const int* __restrict__ as_,
    const float* __restrict__ response_emb, const float* __restrict__ concept_emb,
    const float* __restrict__ nb_adj, const float* __restrict__ bi_self,
    const float* __restrict__ bh_self, const float* __restrict__ b_prop,
    float* __restrict__ ws, const float* __restrict__ stIn, int t) {
    __shared__ alignas(16) float re[92], ssv[92], ceq[92], nsv[92], xprop[184];
    __shared__ alignas(16) float giA[272], ghA[272];
    __shared__ alignas(16) float nsyL[92], pvL[92];
    __shared__ alignas(16) float hnb[NBMAX][92];
    __shared__ alignas(16) float rfp[3][92];
    __shared__ float nbw[NBMAX];
    __shared__ int nblist[NBMAX];
    __shared__ int nnbS;

    const int tid = threadIdx.x;
    const int b = blockIdx.x;
    const int q = qs[b * NT + t], a = as_[b * NT + t];

    // phase 1: vectors + neighbor scan
    if (tid < 90) {
        re[tid] = response_emb[(size_t)a * 90 + tid];
        ssv[tid] = stIn[((size_t)(b * KU + q)) * 90 + tid];
        ceq[tid] = concept_emb[(size_t)q * 90 + tid];
    } else if (tid < 92) { re[tid] = 0.f; ssv[tid] = 0.f; ceq[tid] = 0.f; nsv[tid] = 0.f; }
    if (tid >= 256) {
        const int lane = tid - 256;
        int base = 0;
        for (int ch = 0; ch < 8; ++ch) {
            const int kp = ch * 64 + lane;
            const float nv = nb_adj[(size_t)q * KU + kp];
            const unsigned long long mb = __ballot(nv != 0.f);
            const int idx = base + (int)__popcll(mb & ((1ull << lane) - 1ull));
            if (nv != 0.f && idx < NBMAX) { nblist[idx] = kp; nbw[idx] = nv; }
            base += (int)__popcll(mb);
        }
        if (lane == 0) nnbS = (base < NBMAX) ? base : NBMAX;
    }
    __syncthreads();
    // phase 2: self-GRU matvecs
    if (tid < 270) {
        float a1 = bi_self[tid], a2 = bh_self[tid];
        const float4* w1 = (const float4*)(ws + OFF_WIS + (size_t)tid * 92);
        const float4* w2 = (const float4*)(ws + OFF_WHS + (size_t)tid * 92);
        const float4* rv = (const float4*)re;
        const float4* sv4 = (const float4*)ssv;
#pragma unroll 4
        for (int p = 0; p < 23; ++p) { a1 += dot4(rv[p], w1[p]); a2 += dot4(sv4[p], w2[p]); }
        giA[tid] = a1; ghA[tid] = a2;
    }
    __syncthreads();
    // phase 3: gates -> nsv,xprop (tid<90) | stage hnb (tid>=92)
    if (tid < 90) {
        const float r = sigf(giA[tid] + ghA[tid]);
        const float z = sigf(giA[90 + tid] + ghA[90 + tid]);
        const float g = tanhf_(giA[180 + tid] + r * ghA[180 + tid]);
        const float ns = (1.f - z) * g + z * ssv[tid];
        nsv[tid] = ns;
        xprop[tid] = ns - ssv[tid];
        xprop[90 + tid] = ceq[tid];
    } else if (tid >= 92) {
        const int nnb = nnbS;
        const int nnb4 = (nnb + 3) & ~3;
        for (int i = tid - 92; i < nnb4 * 46; i += 228) {
            const int j = i / 46, c2 = i - j * 46;
            float2 v = make_float2(0.f, 0.f);
            if (j < nnb && c2 < 45)
                v = ((const float2*)(stIn + ((size_t)(b * KU + nblist[j])) * 90))[c2];
            ((float2*)&hnb[j][0])[c2] = v;
        }
    }
    __syncthreads();
    // phase 4: nsync (tid<90) | pvec (90<=tid<180)
    if (tid < 90) {
        const float4* wm = (const float4*)(ws + OFF_SYMID + (size_t)tid * 92);
        const float4* nv4 = (const float4*)nsv;
        float d = 0.f;
#pragma unroll 4
        for (int p = 0; p < 23; ++p) d += dot4(nv4[p], wm[p]);
        nsyL[tid] = d;
    } else if (tid < 180) {
        const int m = tid - 90;
        const float4* wp = (const float4*)(ws + OFF_WPR + (size_t)m * 180);
        const float4* xp = (const float4*)xprop;
        float d = b_prop[m];
#pragma unroll 5
        for (int p = 0; p < 45; ++p) d += dot4(xp[p], wp[p]);
        pvL[m] = fmaxf(d, 0.f);
    }
    __syncthreads();
    // phase 5: reflec partials, 3 groups of 90
    if (tid < 270) {
        const int g = (tid >= 180) ? 2 : ((tid >= 90) ? 1 : 0);
        const int m = tid - g * 90;
        const int nnb = nnbS;
        const float nsym = nsyL[m];
        const float4* wrow = (const float4*)(ws + OFF_SYLO + (size_t)m * 92);
        float racc = 0.f;
        for (int j = g; j < nnb; j += 3) {
            const float4* hj = (const float4*)&hnb[j][0];
            float d = 0.f;
#pragma unroll 4
            for (int p = 0; p < 23; ++p) d += dot4(hj[p], wrow[p]);
            racc += nbw[j] * fmaxf(nsym + ws[OFF_CEB + (size_t)nblist[j] * 90 + m] + d, 0.f);
        }
        rfp[g][m] = racc;
    }
    __syncthreads();
    // phase 6: ABUF
    if (tid < 90) {
        ws[OFF_ABUF + (size_t)b * 92 + tid] = nsyL[tid];
        ws[OFF_ABUF + (size_t)(32 + b) * 92 + tid] = pvL[tid];
        ws[OFF_ABUF + (size_t)(64 + b) * 92 + tid] = rfp[0][tid] + rfp[1][tid] + rfp[2][tid];
    }
}

// ============ K2: 32-row tile, 256 thr, ~45 KB LDS (2 blocks/CU) ============
__global__ __launch_bounds__(256) void skt_tile(
    const int* __restrict__ qs, const float* __restrict__ nb_adj,
    const float* __restrict__ succ_adj, const float* __restrict__ bi_rnn,
    const float* __restrict__ bh_rnn, const float* __restrict__ b_agg,
    const float* __restrict__ W_out, const float* __restrict__ b_out,
    float* __restrict__ ws, const float* __restrict__ stIn, float* __restrict__ stOut,
    float* __restrict__ out, int t) {
    __shared__ alignas(16) float hT[90 * 36];      // transposed states (GEMM A)
    __shared__ alignas(16) float hR[TIL * 92];     // row-major states
    __shared__ alignas(16) float giL[SLOTS * 273];
    __shared__ alignas(16) float gi0L[273], biL[273];
    __shared__ alignas(16) float nsyL[92], pvL[92], rfL[92], baggL[92], woutL[92];
    __shared__ alignas(16) float actb[4][92], infb[4][92];
    __shared__ float nbvL[TIL], svL[TIL];
    __shared__ int rowslotS[TIL], listS[TIL];
    __shared__ int nactS;

    const int tid = threadIdx.x;
    const int bb = blockIdx.x >> 4;
    const int k0 = (blockIdx.x & 15) * TIL;
    const int q = qs[bb * NT + t];

    // ---------- stage ----------
    for (int idx = tid; idx < 45 * TIL; idx += 256) {       // states: lanes->rows (conflict-free)
        const int row = idx & 31, c2 = idx >> 5;
        const float2 v = ((const float2*)(stIn + ((size_t)(bb * KU + k0 + row)) * 90))[c2];
        ((float2*)&hR[row * 92])[c2] = v;
        hT[(2 * c2) * 36 + row] = v.x;
        hT[(2 * c2 + 1) * 36 + row] = v.y;
    }
    if (tid < 92) {
        const int m = tid;
        nsyL[m] = ws[OFF_ABUF + (size_t)bb * 92 + m];
        pvL[m] = ws[OFF_ABUF + (size_t)(32 + bb) * 92 + m];
        rfL[m] = ws[OFF_ABUF + (size_t)(64 + bb) * 92 + m];
        baggL[m] = (m < 90) ? b_agg[m] : 0.f;
        woutL[m] = (m < 90) ? W_out[m] : 0.f;
    } else if (tid < 192) {
        for (int c = tid - 92; c < 273; c += 100) {
            gi0L[c] = (c < 272) ? ws[OFF_GI0 + c] : 0.f;
            biL[c] = (c < 270) ? bi_rnn[c] : 0.f;
        }
    } else if (tid < 224) {
        const int lane = tid - 192;
        const int kg = k0 + lane;
        const float nv = nb_adj[(size_t)q * KU + kg];
        const float sv = succ_adj[(size_t)q * KU + kg];
        nbvL[lane] = nv; svL[lane] = sv;
        const bool act = (nv != 0.f) || (sv != 0.f) || (kg == q);
        const unsigned long long mb = __ballot(act);
        const int rank = (int)__popcll(mb & ((1ull << lane) - 1ull));
        rowslotS[lane] = (act && rank < SLOTS) ? rank : -1;
        if (act && rank < SLOTS) listS[rank] = lane;
        if (lane == 0) { int n = (int)__popcll(mb); nactS = (n < SLOTS) ? n : SLOTS; }
    } else {
        const int l = tid - 224;
        if (l < 4) { actb[l][90] = 0.f; actb[l][91] = 0.f; infb[l][90] = 0.f; infb[l][91] = 0.f; }
        hR[l * 92 + 90] = 0.f; hR[l * 92 + 91] = 0.f;
    }
    __syncthreads();   // #1

    // ---------- GEMM: gh = h @ Wh (+bh), Wh streamed from L2, gate triples per thread ----------
    const int rowg = tid >> 5, tc = tid & 31;
    float acc[4][9];
    if (tc < 30) {
        const int m0 = tc * 3;
#pragma unroll
        for (int r = 0; r < 4; ++r)
#pragma unroll
            for (int j = 0; j < 9; ++j) acc[r][j] = 0.f;
        const float* pw0 = ws + OFF_WHB + m0;
        const float* pw1 = pw0 + 90 * 92;
        const float* pw2 = pw1 + 90 * 92;
#pragma unroll 3
        for (int k = 0; k < 90; ++k) {
            const float4 h = *(const float4*)(hT + k * 36 + rowg * 4);
            const f3v w0 = *(const f3v*)(pw0 + k * 92);
            const f3v w1 = *(const f3v*)(pw1 + k * 92);
            const f3v w2 = *(const f3v*)(pw2 + k * 92);
            const float hv[4] = {h.x, h.y, h.z, h.w};
#pragma unroll
            for (int r = 0; r < 4; ++r) {
                acc[r][0] += hv[r] * w0.x; acc[r][1] += hv[r] * w0.y; acc[r][2] += hv[r] * w0.z;
                acc[r][3] += hv[r] * w1.x; acc[r][4] += hv[r] * w1.y; acc[r][5] += hv[r] * w1.z;
                acc[r][6] += hv[r] * w2.x; acc[r][7] += hv[r] * w2.y; acc[r][8] += hv[r] * w2.z;
            }
        }
        float bhv[9];
#pragma unroll
        for (int g = 0; g < 3; ++g)
#pragma unroll
            for (int i = 0; i < 3; ++i) bhv[g * 3 + i] = bh_rnn[g * 90 + m0 + i];
#pragma unroll
        for (int r = 0; r < 4; ++r)
#pragma unroll
            for (int j = 0; j < 9; ++j) acc[r][j] += bhv[j];
    }

    // ---------- chains (all 4 waves, no barrier vs GEMM) ----------
    {
        const int w = tid >> 6;
        const int lane = tid & 63;
        const int nact = nactS;
        for (int e = w; e < nact; e += 4) {
            const int r = listS[e];
            const float nv = nbvL[r], sv = svL[r];
            const bool isq = (k0 + r == q);
            for (int m = lane; m < 90; m += 64) {
                float s = 0.f;
                if (nv != 0.f) {
                    const float4* wrow = (const float4*)(ws + OFF_SYLO + (size_t)m * 92);
                    const float4* hr4 = (const float4*)&hR[r * 92];
                    float d = 0.f;
#pragma unroll 4
                    for (int p = 0; p < 23; ++p) d += dot4(hr4[p], wrow[p]);
                    s = nv * fmaxf(nsyL[m] + ws[OFF_CEB + (size_t)(k0 + r) * 90 + m] + d, 0.f);
                }
                if (isq) s += rfL[m];
                actb[w][m] = 0.5f * s + 0.5f * sv * pvL[m];
            }
            WAVE_SYNC();
            for (int m = lane; m < 90; m += 64) {
                const float4* wrow = (const float4*)(ws + OFF_AGG + (size_t)m * 92);
                const float4* av = (const float4*)&actb[w][0];
                float d = baggL[m];
#pragma unroll 4
                for (int p = 0; p < 23; ++p) d += dot4(av[p], wrow[p]);
                infb[w][m] = fmaxf(d, 0.f);
            }
            WAVE_SYNC();
            for (int c = lane; c < 270; c += 64) {
                const float4* wrow = (const float4*)(ws + OFF_WIR + (size_t)c * 92);
                const float4* iv = (const float4*)&infb[w][0];
                float d = biL[c];
#pragma unroll 4
                for (int p = 0; p < 23; ++p) d += dot4(iv[p], wrow[p]);
                giL[e * 273 + c] = d;
            }
            WAVE_SYNC();
        }
    }
    __syncthreads();   // #2 — giL complete

    // ---------- gates in registers ----------
    if (tc < 30) {
        const int m0 = tc * 3;
#pragma unroll
        for (int r = 0; r < 4; ++r) {
            const int row = rowg * 4 + r;
            const int slot = rowslotS[row];
            const float* gs = (slot >= 0) ? &giL[slot * 273] : gi0L;
            float hn[3];
#pragma unroll
            for (int i = 0; i < 3; ++i) {
                const int m = m0 + i;
                const float rg = sigf(gs[m] + acc[r][i]);
                const float zg = sigf(gs[90 + m] + acc[r][3 + i]);
                const float gg = tanhf_(gs[180 + m] + rg * acc[r][6 + i]);
                const float hold = hR[row * 92 + m];
                hn[i] = (1.f - zg) * gg + zg * hold;
            }
            hR[row * 92 + m0] = hn[0];
            hR[row * 92 + m0 + 1] = hn[1];
            hR[row * 92 + m0 + 2] = hn[2];
            f3v o; o.x = hn[0]; o.y = hn[1]; o.z = hn[2];
            *(f3v*)(stOut + ((size_t)(bb * KU + k0 + row)) * 90 + m0) = o;
        }
    }
    __syncthreads();   // #3 — hR = new states

    // ---------- out head: 8 threads/row + shuffle reduce ----------
    {
        const int row = tid >> 3, j = tid & 7;
        const int mstart = j * 12;
        float p = 0.f;
        for (int m = mstart; m < mstart + 12 && m < 90; ++m) p += hR[row * 92 + m] * woutL[m];
#pragma unroll
        for (int o = 1; o < 8; o <<= 1) p += __shfl_xor(p, o);
        if (j == 0)
            out[(size_t)t * NB * KU + (size_t)bb * KU + k0 + row] = sigf(p + b_out[0]);
    }
}

extern "C" void kernel_launch(void* const* d_in, const int* in_sizes, int n_in,
                              void* d_out, int out_size, void* d_ws, size_t ws_size,
                              hipStream_t stream) {
    const int* questions = (const int*)d_in[0];
    const int* answers = (const int*)d_in[1];
    const float* response_emb = (const float*)d_in[2];
    const float* concept_emb = (const float*)d_in[3];
    const float* nb_adj = (const float*)d_in[4];
    const float* succ_adj = (const float*)d_in[5];
    const float* Wi_self = (const float*)d_in[6];
    const float* Wh_self = (const float*)d_in[7];
    const float* bi_self = (const float*)d_in[8];
    const float* bh_self = (const float*)d_in[9];
    const float* Wi_rnn = (const float*)d_in[10];
    const float* Wh_rnn = (const float*)d_in[11];
    const float* bi_rnn = (const float*)d_in[12];
    const float* bh_rnn = (const float*)d_in[13];
    const float* W_sync = (const float*)d_in[14];
    const float* b_sync = (const float*)d_in[15];
    const float* W_prop = (const float*)d_in[16];
    const float* b_prop = (const float*)d_in[17];
    const float* W_agg = (const float*)d_in[18];
    const float* b_agg = (const float*)d_in[19];
    const float* W_out = (const float*)d_in[20];
    const float* b_out = (const float*)d_in[21];

    float* out = (float*)d_out;
    float* stFinal = out + (size_t)NT * NB * KU;   // states region of d_out
    float* ws = (float*)d_ws;

    hipMemsetAsync(stFinal, 0, (size_t)NB * KU * 90 * sizeof(float), stream);
    skt_prep<<<177, 256, 0, stream>>>(concept_emb, W_sync, b_sync, W_agg, W_prop, Wi_rnn,
                                      Wh_rnn, Wi_self, Wh_self, bi_rnn, b_agg, ws);
    for (int t = 0; t < NT; ++t) {
        const float* sin = (t & 1) ? ws : stFinal;
        float* sout = (t & 1) ? stFinal : ws;
        skt_batch<<<NB, 320, 0, stream>>>(questions, answers, response_emb, concept_emb,
                                          nb_adj, bi_self, bh_self, b_prop, ws, sin, t);
        skt_tile<<<NB * 16, 256, 0, stream>>>(questions, nb_adj, succ_adj, bi_rnn, bh_rnn,
                                              b_agg, W_out, b_out, ws, sin, sout, out, t);
    }
}